// Round 1
// baseline (1293.641 us; speedup 1.0000x reference)
//
#include <hip/hip_runtime.h>

constexpr int NN = 100000;
constexpr int NE = 640000;
constexpr int D  = 128;

// ---------------------------------------------------------------------------
// Phase 1a: hpre = (1+eps) * x   (accumulator initialization, fused GINE term)
// ---------------------------------------------------------------------------
__global__ __launch_bounds__(256) void k_init(const float* __restrict__ x,
                                              const float* __restrict__ eps,
                                              float* __restrict__ hpre) {
    int i = blockIdx.x * 256 + threadIdx.x;
    const int n4 = NN * D / 4;
    if (i >= n4) return;
    const float s = 1.0f + eps[0];
    float4 v = reinterpret_cast<const float4*>(x)[i];
    v.x *= s; v.y *= s; v.z *= s; v.w *= s;
    reinterpret_cast<float4*>(hpre)[i] = v;
}

// ---------------------------------------------------------------------------
// Phase 1b: hpre[dst] += relu(x[src] + edge_attr)   (atomic scatter-add)
// One thread per (edge, 4-float chunk): 32 consecutive threads cover one edge
// -> coalesced edge_attr reads, contiguous x gathers.
// ---------------------------------------------------------------------------
__global__ __launch_bounds__(256) void k_scatter(const float* __restrict__ x,
                                                 const int* __restrict__ src,
                                                 const int* __restrict__ dst,
                                                 const float* __restrict__ ea,
                                                 float* __restrict__ hpre) {
    unsigned gid = blockIdx.x * 256 + threadIdx.x;
    unsigned e = gid >> 5;
    unsigned c = gid & 31;
    if (e >= NE) return;
    const int s = src[e];
    const int d = dst[e];
    float4 a = reinterpret_cast<const float4*>(x + (size_t)s * D)[c];
    float4 b = reinterpret_cast<const float4*>(ea + (size_t)e * D)[c];
    float4 m;
    m.x = fmaxf(a.x + b.x, 0.0f);
    m.y = fmaxf(a.y + b.y, 0.0f);
    m.z = fmaxf(a.z + b.z, 0.0f);
    m.w = fmaxf(a.w + b.w, 0.0f);
    float* o = hpre + (size_t)d * D + c * 4;
    atomicAdd(o + 0, m.x);
    atomicAdd(o + 1, m.y);
    atomicAdd(o + 2, m.z);
    atomicAdd(o + 3, m.w);
}

// ---------------------------------------------------------------------------
// Phase 2: one MLP layer  out = act(in @ W + bias)
// W (128x128 f32 = 64 KB) staged in LDS. Block = 256 threads = 4 waves.
// Wave w owns output columns [w*32, w*32+32); lane = row within 64-row tile.
// W reads are wave-uniform -> LDS broadcast, no bank conflicts.
// In-place safe (in == out): each block reads only rows it writes, and a
// __syncthreads() separates all loads from all stores.
// ---------------------------------------------------------------------------
template<bool RELU>
__global__ __launch_bounds__(256) void k_mlp(const float* in,
                                             const float* __restrict__ W,
                                             const float* __restrict__ bias,
                                             float* out) {
    __shared__ float Wl[D * D];  // 64 KB
    {
        const float4* Wv = reinterpret_cast<const float4*>(W);
        float4* Wlv = reinterpret_cast<float4*>(Wl);
        for (int i = threadIdx.x; i < D * D / 4; i += 256) Wlv[i] = Wv[i];
    }
    __syncthreads();

    const int wave = threadIdx.x >> 6;
    const int lane = threadIdx.x & 63;
    const int row  = blockIdx.x * 64 + lane;
    const bool valid = row < NN;

    float acc[32];
#pragma unroll
    for (int c = 0; c < 32; ++c) acc[c] = 0.0f;

    const float* rowp = in + (size_t)row * D;
    for (int kk = 0; kk < D; kk += 16) {
        float rr[16];
        if (valid) {
#pragma unroll
            for (int q = 0; q < 4; ++q)
                *reinterpret_cast<float4*>(&rr[q * 4]) =
                    reinterpret_cast<const float4*>(rowp + kk)[q];
        } else {
#pragma unroll
            for (int q = 0; q < 16; ++q) rr[q] = 0.0f;
        }
#pragma unroll
        for (int k = 0; k < 16; ++k) {
            const float a = rr[k];
            const float* wrow = &Wl[(kk + k) * D + wave * 32];
#pragma unroll
            for (int c = 0; c < 32; c += 4) {
                float4 w = *reinterpret_cast<const float4*>(wrow + c);
                acc[c + 0] = fmaf(a, w.x, acc[c + 0]);
                acc[c + 1] = fmaf(a, w.y, acc[c + 1]);
                acc[c + 2] = fmaf(a, w.z, acc[c + 2]);
                acc[c + 3] = fmaf(a, w.w, acc[c + 3]);
            }
        }
    }

    __syncthreads();  // all loads (incl. other waves reading our rows) done

    if (valid) {
#pragma unroll
        for (int c = 0; c < 32; c += 4) {
            float4 bb = *reinterpret_cast<const float4*>(bias + wave * 32 + c);
            float4 o;
            o.x = acc[c + 0] + bb.x;
            o.y = acc[c + 1] + bb.y;
            o.z = acc[c + 2] + bb.z;
            o.w = acc[c + 3] + bb.w;
            if (RELU) {
                o.x = fmaxf(o.x, 0.0f); o.y = fmaxf(o.y, 0.0f);
                o.z = fmaxf(o.z, 0.0f); o.w = fmaxf(o.w, 0.0f);
            }
            reinterpret_cast<float4*>(out + (size_t)row * D + wave * 32)[c / 4] = o;
        }
    }
}

// ---------------------------------------------------------------------------
extern "C" void kernel_launch(void* const* d_in, const int* in_sizes, int n_in,
                              void* d_out, int out_size, void* d_ws, size_t ws_size,
                              hipStream_t stream) {
    const float* x   = (const float*)d_in[0];
    const int*   ei  = (const int*)d_in[1];   // edge_index, int32, [2, NE] row-major
    const float* ea  = (const float*)d_in[2];
    const float* eps = (const float*)d_in[3];
    const float* W1  = (const float*)d_in[4];
    const float* b1  = (const float*)d_in[5];
    const float* W2  = (const float*)d_in[6];
    const float* b2  = (const float*)d_in[7];
    float* out  = (float*)d_out;
    float* hpre = (float*)d_ws;               // 100000*128*4 = 51.2 MB

    const int* src = ei;        // edge_index[0]
    const int* dst = ei + NE;   // edge_index[1]

    // hpre = (1+eps)*x
    k_init<<<(NN * D / 4) / 256, 256, 0, stream>>>(x, eps, hpre);
    // hpre[dst] += relu(x[src] + edge_attr)
    k_scatter<<<(NE * 32) / 256, 256, 0, stream>>>(x, src, dst, ea, hpre);
    // out = relu(hpre @ W1 + b1)
    k_mlp<true><<<(NN + 63) / 64, 256, 0, stream>>>(hpre, W1, b1, out);
    // out = out @ W2 + b2   (in-place)
    k_mlp<false><<<(NN + 63) / 64, 256, 0, stream>>>(out, W2, b2, out);
}

// Round 2
// 424.181 us; speedup vs baseline: 3.0497x; 3.0497x over previous
//
#include <hip/hip_runtime.h>

constexpr int NN = 100000;
constexpr int NE = 640000;
constexpr int D  = 128;
constexpr int NB = (NN + 255) / 256;  // 391 scan blocks

// ---------------------------------------------------------------------------
// Counting-sort of edges by dst: zero -> histogram -> 2-level exclusive scan
// -> permutation. Replaces 82M f32 atomics with 1.28M int atomics.
// ---------------------------------------------------------------------------
__global__ __launch_bounds__(256) void k_zero(int* __restrict__ cnt) {
    int i = blockIdx.x * 256 + threadIdx.x;
    if (i < NN) cnt[i] = 0;
}

__global__ __launch_bounds__(256) void k_hist(const int* __restrict__ dst,
                                              int* __restrict__ cnt) {
    int e = blockIdx.x * 256 + threadIdx.x;
    if (e < NE) atomicAdd(&cnt[dst[e]], 1);
}

__global__ __launch_bounds__(256) void k_bsum(const int* __restrict__ cnt,
                                              int* __restrict__ bsum) {
    int i = blockIdx.x * 256 + threadIdx.x;
    int v = (i < NN) ? cnt[i] : 0;
#pragma unroll
    for (int s = 32; s; s >>= 1) v += __shfl_down(v, s, 64);
    __shared__ int w[4];
    if ((threadIdx.x & 63) == 0) w[threadIdx.x >> 6] = v;
    __syncthreads();
    if (threadIdx.x == 0) bsum[blockIdx.x] = w[0] + w[1] + w[2] + w[3];
}

__global__ __launch_bounds__(512) void k_scan_bsum(const int* __restrict__ bsum,
                                                   int* __restrict__ bboff) {
    int t = threadIdx.x, lane = t & 63;
    int v = (t < NB) ? bsum[t] : 0;
    int incl = v;
#pragma unroll
    for (int s = 1; s < 64; s <<= 1) {
        int u = __shfl_up(incl, s, 64);
        if (lane >= s) incl += u;
    }
    __shared__ int wt[8], wp[8];
    if (lane == 63) wt[t >> 6] = incl;
    __syncthreads();
    if (t == 0) { int run = 0; for (int i = 0; i < 8; ++i) { wp[i] = run; run += wt[i]; } }
    __syncthreads();
    if (t < NB) bboff[t] = incl - v + wp[t >> 6];
}

__global__ __launch_bounds__(256) void k_scan_final(const int* __restrict__ cnt,
                                                    const int* __restrict__ bboff,
                                                    int* __restrict__ off,
                                                    int* __restrict__ cur) {
    int b = blockIdx.x, t = threadIdx.x, lane = t & 63;
    int i = b * 256 + t;
    int v = (i < NN) ? cnt[i] : 0;
    int incl = v;
#pragma unroll
    for (int s = 1; s < 64; s <<= 1) {
        int u = __shfl_up(incl, s, 64);
        if (lane >= s) incl += u;
    }
    __shared__ int wt[4], wp[4];
    if (lane == 63) wt[t >> 6] = incl;
    __syncthreads();
    if (t == 0) { int run = 0; for (int q = 0; q < 4; ++q) { wp[q] = run; run += wt[q]; } }
    __syncthreads();
    int excl = incl - v + wp[t >> 6] + bboff[b];
    if (i < NN) { off[i] = excl; cur[i] = excl; }
    if (i == 0) off[NN] = NE;
}

__global__ __launch_bounds__(256) void k_perm(const int* __restrict__ dst,
                                              int* __restrict__ cur,
                                              int* __restrict__ perm) {
    int e = blockIdx.x * 256 + threadIdx.x;
    if (e < NE) { int p = atomicAdd(&cur[dst[e]], 1); perm[p] = e; }
}

// ---------------------------------------------------------------------------
// Aggregation: one wave per node. Each lane owns 2 of the 128 features.
// h[n] = (1+eps)*x[n] + sum_{e: dst[e]==n} relu(x[src[e]] + ea[e])
// Writes each output row exactly once -> no f32 atomics, no RMW write blowup.
// ---------------------------------------------------------------------------
__global__ __launch_bounds__(256) void k_agg(const float* __restrict__ x,
                                             const int* __restrict__ src,
                                             const float* __restrict__ ea,
                                             const int* __restrict__ off,
                                             const int* __restrict__ perm,
                                             const float* __restrict__ eps,
                                             float* __restrict__ h) {
    int wave = threadIdx.x >> 6;
    int lane = threadIdx.x & 63;
    int n = blockIdx.x * 4 + wave;
    if (n >= NN) return;
    int j0 = off[n], j1 = off[n + 1];
    float2 acc = {0.0f, 0.0f};
    for (int j = j0; j < j1; ++j) {
        int e = perm[j];
        int s = src[e];
        float2 a  = *reinterpret_cast<const float2*>(x  + (size_t)s * D + lane * 2);
        float2 bb = *reinterpret_cast<const float2*>(ea + (size_t)e * D + lane * 2);
        acc.x += fmaxf(a.x + bb.x, 0.0f);
        acc.y += fmaxf(a.y + bb.y, 0.0f);
    }
    float sc = 1.0f + eps[0];
    float2 xx = *reinterpret_cast<const float2*>(x + (size_t)n * D + lane * 2);
    float2 o;
    o.x = fmaf(sc, xx.x, acc.x);
    o.y = fmaf(sc, xx.y, acc.y);
    *reinterpret_cast<float2*>(h + (size_t)n * D + lane * 2) = o;
}

// ---------------------------------------------------------------------------
// MLP layer out = act(in @ W + bias), W staged in LDS, wave-uniform W reads.
// In-place safe: each block reads only the 64 rows it writes; __syncthreads()
// separates all loads from all stores.
// ---------------------------------------------------------------------------
template<bool RELU>
__global__ __launch_bounds__(256) void k_mlp(const float* in,
                                             const float* __restrict__ W,
                                             const float* __restrict__ bias,
                                             float* out) {
    __shared__ float Wl[D * D];  // 64 KB
    {
        const float4* Wv = reinterpret_cast<const float4*>(W);
        float4* Wlv = reinterpret_cast<float4*>(Wl);
        for (int i = threadIdx.x; i < D * D / 4; i += 256) Wlv[i] = Wv[i];
    }
    __syncthreads();

    const int wave = threadIdx.x >> 6;
    const int lane = threadIdx.x & 63;
    const int row  = blockIdx.x * 64 + lane;
    const bool valid = row < NN;

    float acc[32];
#pragma unroll
    for (int c = 0; c < 32; ++c) acc[c] = 0.0f;

    const float* rowp = in + (size_t)row * D;
    for (int kk = 0; kk < D; kk += 16) {
        float rr[16];
        if (valid) {
#pragma unroll
            for (int q = 0; q < 4; ++q)
                *reinterpret_cast<float4*>(&rr[q * 4]) =
                    reinterpret_cast<const float4*>(rowp + kk)[q];
        } else {
#pragma unroll
            for (int q = 0; q < 16; ++q) rr[q] = 0.0f;
        }
#pragma unroll
        for (int k = 0; k < 16; ++k) {
            const float a = rr[k];
            const float* wrow = &Wl[(kk + k) * D + wave * 32];
#pragma unroll
            for (int c = 0; c < 32; c += 4) {
                float4 w = *reinterpret_cast<const float4*>(wrow + c);
                acc[c + 0] = fmaf(a, w.x, acc[c + 0]);
                acc[c + 1] = fmaf(a, w.y, acc[c + 1]);
                acc[c + 2] = fmaf(a, w.z, acc[c + 2]);
                acc[c + 3] = fmaf(a, w.w, acc[c + 3]);
            }
        }
    }

    __syncthreads();  // all row reads complete before any in-place stores

    if (valid) {
#pragma unroll
        for (int c = 0; c < 32; c += 4) {
            float4 bb = *reinterpret_cast<const float4*>(bias + wave * 32 + c);
            float4 o;
            o.x = acc[c + 0] + bb.x;
            o.y = acc[c + 1] + bb.y;
            o.z = acc[c + 2] + bb.z;
            o.w = acc[c + 3] + bb.w;
            if (RELU) {
                o.x = fmaxf(o.x, 0.0f); o.y = fmaxf(o.y, 0.0f);
                o.z = fmaxf(o.z, 0.0f); o.w = fmaxf(o.w, 0.0f);
            }
            reinterpret_cast<float4*>(out + (size_t)row * D + wave * 32)[c / 4] = o;
        }
    }
}

// ---------------------------------------------------------------------------
extern "C" void kernel_launch(void* const* d_in, const int* in_sizes, int n_in,
                              void* d_out, int out_size, void* d_ws, size_t ws_size,
                              hipStream_t stream) {
    const float* x   = (const float*)d_in[0];
    const int*   ei  = (const int*)d_in[1];   // int32 [2, NE]
    const float* ea  = (const float*)d_in[2];
    const float* eps = (const float*)d_in[3];
    const float* W1  = (const float*)d_in[4];
    const float* b1  = (const float*)d_in[5];
    const float* W2  = (const float*)d_in[6];
    const float* b2  = (const float*)d_in[7];
    float* out = (float*)d_out;

    const int* src = ei;        // edge_index[0]
    const int* dst = ei + NE;   // edge_index[1]

    // workspace layout (~3.8 MB total)
    int* cnt   = (int*)d_ws;
    int* off   = cnt + NN;        // NN+1
    int* cur   = off + NN + 1;
    int* bsum  = cur + NN;
    int* bboff = bsum + NB;
    int* perm  = bboff + NB;      // NE

    k_zero      <<<NB,               256, 0, stream>>>(cnt);
    k_hist      <<<(NE + 255) / 256, 256, 0, stream>>>(dst, cnt);
    k_bsum      <<<NB,               256, 0, stream>>>(cnt, bsum);
    k_scan_bsum <<<1,                512, 0, stream>>>(bsum, bboff);
    k_scan_final<<<NB,               256, 0, stream>>>(cnt, bboff, off, cur);
    k_perm      <<<(NE + 255) / 256, 256, 0, stream>>>(dst, cur, perm);

    // h -> d_out (aggregation writes every row exactly once)
    k_agg<<<(NN + 3) / 4, 256, 0, stream>>>(x, src, ea, off, perm, eps, out);
    // in-place MLP
    k_mlp<true> <<<(NN + 63) / 64, 256, 0, stream>>>(out, W1, b1, out);
    k_mlp<false><<<(NN + 63) / 64, 256, 0, stream>>>(out, W2, b2, out);
}

// Round 3
// 305.868 us; speedup vs baseline: 4.2294x; 1.3868x over previous
//
#include <hip/hip_runtime.h>

constexpr int NN = 100000;
constexpr int NE = 640000;
constexpr int D  = 128;
constexpr int NB = (NN + 255) / 256;  // 391

typedef __attribute__((ext_vector_type(8))) short bf16x8;
typedef __attribute__((ext_vector_type(4))) float f32x4;

__device__ __forceinline__ short f2bf(float f) {
    union { float f; unsigned u; } v; v.f = f;
    unsigned r = v.u + 0x7FFF + ((v.u >> 16) & 1);
    return (short)(r >> 16);
}
__device__ __forceinline__ float bf2f(short h) {
    union { unsigned u; float f; } v;
    v.u = ((unsigned)(unsigned short)h) << 16;
    return v.f;
}

// ---------------------------------------------------------------------------
// Counting sort of edges by dst (histogram -> scan -> permutation)
// ---------------------------------------------------------------------------
__global__ __launch_bounds__(256) void k_zero(int* __restrict__ cnt) {
    int i = blockIdx.x * 256 + threadIdx.x;
    if (i < NN) cnt[i] = 0;
}

__global__ __launch_bounds__(256) void k_hist(const int* __restrict__ dst,
                                              int* __restrict__ cnt) {
    int e = blockIdx.x * 256 + threadIdx.x;
    if (e < NE) atomicAdd(&cnt[dst[e]], 1);
}

__global__ __launch_bounds__(256) void k_bsum(const int* __restrict__ cnt,
                                              int* __restrict__ bsum) {
    int i = blockIdx.x * 256 + threadIdx.x;
    int v = (i < NN) ? cnt[i] : 0;
#pragma unroll
    for (int s = 32; s; s >>= 1) v += __shfl_down(v, s, 64);
    __shared__ int w[4];
    if ((threadIdx.x & 63) == 0) w[threadIdx.x >> 6] = v;
    __syncthreads();
    if (threadIdx.x == 0) bsum[blockIdx.x] = w[0] + w[1] + w[2] + w[3];
}

__global__ __launch_bounds__(512) void k_scan_bsum(const int* __restrict__ bsum,
                                                   int* __restrict__ bboff) {
    int t = threadIdx.x, lane = t & 63;
    int v = (t < NB) ? bsum[t] : 0;
    int incl = v;
#pragma unroll
    for (int s = 1; s < 64; s <<= 1) {
        int u = __shfl_up(incl, s, 64);
        if (lane >= s) incl += u;
    }
    __shared__ int wt[8], wp[8];
    if (lane == 63) wt[t >> 6] = incl;
    __syncthreads();
    if (t == 0) { int run = 0; for (int i = 0; i < 8; ++i) { wp[i] = run; run += wt[i]; } }
    __syncthreads();
    if (t < NB) bboff[t] = incl - v + wp[t >> 6];
}

__global__ __launch_bounds__(256) void k_scan_final(const int* __restrict__ cnt,
                                                    const int* __restrict__ bboff,
                                                    int* __restrict__ off,
                                                    int* __restrict__ cur) {
    int b = blockIdx.x, t = threadIdx.x, lane = t & 63;
    int i = b * 256 + t;
    int v = (i < NN) ? cnt[i] : 0;
    int incl = v;
#pragma unroll
    for (int s = 1; s < 64; s <<= 1) {
        int u = __shfl_up(incl, s, 64);
        if (lane >= s) incl += u;
    }
    __shared__ int wt[4], wp[4];
    if (lane == 63) wt[t >> 6] = incl;
    __syncthreads();
    if (t == 0) { int run = 0; for (int q = 0; q < 4; ++q) { wp[q] = run; run += wt[q]; } }
    __syncthreads();
    int excl = incl - v + wp[t >> 6] + bboff[b];
    if (i < NN) { off[i] = excl; cur[i] = excl; }
    if (i == 0) off[NN] = NE;
}

__global__ __launch_bounds__(256) void k_perm(const int* __restrict__ dst,
                                              const int* __restrict__ src,
                                              int* __restrict__ cur,
                                              int2* __restrict__ ps) {
    int e = blockIdx.x * 256 + threadIdx.x;
    if (e < NE) {
        int p = atomicAdd(&cur[dst[e]], 1);
        int2 v; v.x = e; v.y = src[e];
        ps[p] = v;
    }
}

// ---------------------------------------------------------------------------
// Aggregation: one wave per node, 8-edge software pipeline for MLP.
// h[n] = (1+eps)*x[n] + sum relu(x[src]+ea)   -> d_out (f32)
// ---------------------------------------------------------------------------
__global__ __launch_bounds__(256) void k_agg(const float* __restrict__ x,
                                             const float* __restrict__ ea,
                                             const int* __restrict__ off,
                                             const int2* __restrict__ ps,
                                             const float* __restrict__ eps,
                                             float* __restrict__ h) {
    int wave = threadIdx.x >> 6;
    int lane = threadIdx.x & 63;
    int n = blockIdx.x * 4 + wave;
    if (n >= NN) return;
    int j0 = off[n], j1 = off[n + 1];
    const int lo2 = lane * 2;
    float2 acc; acc.x = 0.0f; acc.y = 0.0f;

    for (int j = j0; j < j1; j += 8) {
        int ee[8], ss[8];
#pragma unroll
        for (int q = 0; q < 8; ++q) {
            int jj = j + q; jj = (jj < j1) ? jj : (j1 - 1);
            int2 p = ps[jj];
            ee[q] = p.x; ss[q] = p.y;
        }
        float2 xa[8], eb[8];
#pragma unroll
        for (int q = 0; q < 8; ++q) {
            xa[q] = *reinterpret_cast<const float2*>(x  + (size_t)ss[q] * D + lo2);
            eb[q] = *reinterpret_cast<const float2*>(ea + (size_t)ee[q] * D + lo2);
        }
#pragma unroll
        for (int q = 0; q < 8; ++q) {
            float mx = fmaxf(xa[q].x + eb[q].x, 0.0f);
            float my = fmaxf(xa[q].y + eb[q].y, 0.0f);
            bool ok = (j + q) < j1;
            acc.x += ok ? mx : 0.0f;
            acc.y += ok ? my : 0.0f;
        }
    }
    float sc = 1.0f + eps[0];
    float2 xx = *reinterpret_cast<const float2*>(x + (size_t)n * D + lo2);
    float2 o;
    o.x = fmaf(sc, xx.x, acc.x);
    o.y = fmaf(sc, xx.y, acc.y);
    *reinterpret_cast<float2*>(h + (size_t)n * D + lo2) = o;
}

// ---------------------------------------------------------------------------
// MLP layer via bf16x3 MFMA: out = act(A @ W + bias), all f32 in memory.
// A split hi/lo in-register after load; W transposed+split into padded LDS.
// Block: 256 thr = 4 waves, 128 rows (2 m-subtiles of 16 per wave).
// ---------------------------------------------------------------------------
template<bool RELU>
__global__ __launch_bounds__(256) void k_gemm(const float* __restrict__ A,
                                              const float* __restrict__ W,
                                              const float* __restrict__ bias,
                                              float* __restrict__ out) {
    constexpr int LDW = 136;  // padded k-stride (shorts): 272 B = 17*16 B
    __shared__ short Whi[128 * LDW];
    __shared__ short Wlo[128 * LDW];

    // stage: W [k][n] f32 -> transposed bf16 hi/lo [n][k]
    for (int idx = threadIdx.x; idx < 128 * 128; idx += 256) {
        int k = idx >> 7, n = idx & 127;
        float w = W[idx];
        short hi = f2bf(w);
        short lo = f2bf(w - bf2f(hi));
        Whi[n * LDW + k] = hi;
        Wlo[n * LDW + k] = lo;
    }
    __syncthreads();

    const int wave = threadIdx.x >> 6;
    const int lane = threadIdx.x & 63;
    const int r = lane & 15;      // A-row / B-col / D-col index
    const int g = lane >> 4;      // k-group (8 k per group)

    const long mb = (long)blockIdx.x * 128 + wave * 16;  // subtile0; subtile1 = +64

    f32x4 acc[2][8];
#pragma unroll
    for (int mt = 0; mt < 2; ++mt)
#pragma unroll
        for (int nt = 0; nt < 8; ++nt) {
            acc[mt][nt].x = 0.f; acc[mt][nt].y = 0.f;
            acc[mt][nt].z = 0.f; acc[mt][nt].w = 0.f;
        }

#pragma unroll
    for (int kc = 0; kc < 4; ++kc) {
        const int k0 = kc * 32;
        bf16x8 ahi[2], alo[2];
#pragma unroll
        for (int mt = 0; mt < 2; ++mt) {
            long row = mb + mt * 64 + r;
            row = (row < NN) ? row : (NN - 1);
            const float* ap = A + row * D + k0 + g * 8;
            float4 v0 = reinterpret_cast<const float4*>(ap)[0];
            float4 v1 = reinterpret_cast<const float4*>(ap)[1];
            float vals[8] = {v0.x, v0.y, v0.z, v0.w, v1.x, v1.y, v1.z, v1.w};
#pragma unroll
            for (int i = 0; i < 8; ++i) {
                short hb = f2bf(vals[i]);
                ahi[mt][i] = hb;
                alo[mt][i] = f2bf(vals[i] - bf2f(hb));
            }
        }
#pragma unroll
        for (int nt = 0; nt < 8; ++nt) {
            const int wb = (nt * 16 + r) * LDW + k0 + g * 8;
            bf16x8 whi = *reinterpret_cast<const bf16x8*>(&Whi[wb]);
            bf16x8 wlo = *reinterpret_cast<const bf16x8*>(&Wlo[wb]);
#pragma unroll
            for (int mt = 0; mt < 2; ++mt) {
                acc[mt][nt] = __builtin_amdgcn_mfma_f32_16x16x32_bf16(ahi[mt], whi, acc[mt][nt], 0, 0, 0);
                acc[mt][nt] = __builtin_amdgcn_mfma_f32_16x16x32_bf16(ahi[mt], wlo, acc[mt][nt], 0, 0, 0);
                acc[mt][nt] = __builtin_amdgcn_mfma_f32_16x16x32_bf16(alo[mt], whi, acc[mt][nt], 0, 0, 0);
            }
        }
    }

    // epilogue: D col = r (per 16-tile), row = g*4 + q
#pragma unroll
    for (int nt = 0; nt < 8; ++nt) {
        const int col = nt * 16 + r;
        const float bb = bias[col];
#pragma unroll
        for (int mt = 0; mt < 2; ++mt) {
#pragma unroll
            for (int q = 0; q < 4; ++q) {
                long row = mb + mt * 64 + g * 4 + q;
                if (row < NN) {
                    float v = acc[mt][nt][q] + bb;
                    if (RELU) v = fmaxf(v, 0.0f);
                    out[row * D + col] = v;
                }
            }
        }
    }
}

// ---------------------------------------------------------------------------
extern "C" void kernel_launch(void* const* d_in, const int* in_sizes, int n_in,
                              void* d_out, int out_size, void* d_ws, size_t ws_size,
                              hipStream_t stream) {
    const float* x   = (const float*)d_in[0];
    const int*   ei  = (const int*)d_in[1];   // int32 [2, NE]
    const float* ea  = (const float*)d_in[2];
    const float* eps = (const float*)d_in[3];
    const float* W1  = (const float*)d_in[4];
    const float* b1  = (const float*)d_in[5];
    const float* W2  = (const float*)d_in[6];
    const float* b2  = (const float*)d_in[7];
    float* out = (float*)d_out;

    const int* src = ei;
    const int* dst = ei + NE;

    // ws layout: sort arrays live in the front 6.4 MB; g (51.2 MB) overlays
    // them starting at 0 — valid because all sort data is dead after k_agg.
    int* base  = (int*)d_ws;
    int* cnt   = base;                 // NN
    int* off   = cnt + NN;             // NN+1
    int* cur   = off + NN + 1;         // NN
    int* bsum  = cur + NN;             // NB
    int* bboff = bsum + NB;            // NB
    size_t ps_off = ((size_t)(3 * NN + 1 + 2 * NB) + 1) & ~(size_t)1;
    int2* ps   = (int2*)(base + ps_off);  // NE int2
    float* g   = (float*)d_ws;            // [NN, D] f32, overlays sort arrays

    k_zero      <<<NB,               256, 0, stream>>>(cnt);
    k_hist      <<<(NE + 255) / 256, 256, 0, stream>>>(dst, cnt);
    k_bsum      <<<NB,               256, 0, stream>>>(cnt, bsum);
    k_scan_bsum <<<1,                512, 0, stream>>>(bsum, bboff);
    k_scan_final<<<NB,               256, 0, stream>>>(cnt, bboff, off, cur);
    k_perm      <<<(NE + 255) / 256, 256, 0, stream>>>(dst, src, cur, ps);

    // h -> d_out
    k_agg<<<(NN + 3) / 4, 256, 0, stream>>>(x, ea, off, ps, eps, out);
    // g = relu(h @ W1 + b1)   (reads d_out, writes ws)
    k_gemm<true> <<<(NN + 127) / 128, 256, 0, stream>>>(out, W1, b1, g);
    // out = g @ W2 + b2       (reads ws, writes d_out)
    k_gemm<false><<<(NN + 127) / 128, 256, 0, stream>>>(g, W2, b2, out);
}

// Round 4
// 304.604 us; speedup vs baseline: 4.2470x; 1.0042x over previous
//
#include <hip/hip_runtime.h>

constexpr int NN = 100000;
constexpr int NE = 640000;
constexpr int D  = 128;
constexpr int NB = (NN + 255) / 256;  // 391

typedef __attribute__((ext_vector_type(8))) short bf16x8;
typedef __attribute__((ext_vector_type(4))) float f32x4;

__device__ __forceinline__ short f2bf(float f) {
    union { float f; unsigned u; } v; v.f = f;
    unsigned r = v.u + 0x7FFF + ((v.u >> 16) & 1);
    return (short)(r >> 16);
}
__device__ __forceinline__ float bf2f(short h) {
    union { unsigned u; float f; } v;
    v.u = ((unsigned)(unsigned short)h) << 16;
    return v.f;
}

// ---------------------------------------------------------------------------
// Counting sort of edges by dst (histogram -> scan -> permutation)
// ---------------------------------------------------------------------------
__global__ __launch_bounds__(256) void k_zero(int* __restrict__ cnt) {
    int i = blockIdx.x * 256 + threadIdx.x;
    if (i < NN) cnt[i] = 0;
}

__global__ __launch_bounds__(256) void k_hist(const int* __restrict__ dst,
                                              int* __restrict__ cnt) {
    int e = blockIdx.x * 256 + threadIdx.x;
    if (e < NE) atomicAdd(&cnt[dst[e]], 1);
}

__global__ __launch_bounds__(256) void k_bsum(const int* __restrict__ cnt,
                                              int* __restrict__ bsum) {
    int i = blockIdx.x * 256 + threadIdx.x;
    int v = (i < NN) ? cnt[i] : 0;
#pragma unroll
    for (int s = 32; s; s >>= 1) v += __shfl_down(v, s, 64);
    __shared__ int w[4];
    if ((threadIdx.x & 63) == 0) w[threadIdx.x >> 6] = v;
    __syncthreads();
    if (threadIdx.x == 0) bsum[blockIdx.x] = w[0] + w[1] + w[2] + w[3];
}

__global__ __launch_bounds__(512) void k_scan_bsum(const int* __restrict__ bsum,
                                                   int* __restrict__ bboff) {
    int t = threadIdx.x, lane = t & 63;
    int v = (t < NB) ? bsum[t] : 0;
    int incl = v;
#pragma unroll
    for (int s = 1; s < 64; s <<= 1) {
        int u = __shfl_up(incl, s, 64);
        if (lane >= s) incl += u;
    }
    __shared__ int wt[8], wp[8];
    if (lane == 63) wt[t >> 6] = incl;
    __syncthreads();
    if (t == 0) { int run = 0; for (int i = 0; i < 8; ++i) { wp[i] = run; run += wt[i]; } }
    __syncthreads();
    if (t < NB) bboff[t] = incl - v + wp[t >> 6];
}

__global__ __launch_bounds__(256) void k_scan_final(const int* __restrict__ cnt,
                                                    const int* __restrict__ bboff,
                                                    int* __restrict__ off,
                                                    int* __restrict__ cur) {
    int b = blockIdx.x, t = threadIdx.x, lane = t & 63;
    int i = b * 256 + t;
    int v = (i < NN) ? cnt[i] : 0;
    int incl = v;
#pragma unroll
    for (int s = 1; s < 64; s <<= 1) {
        int u = __shfl_up(incl, s, 64);
        if (lane >= s) incl += u;
    }
    __shared__ int wt[4], wp[4];
    if (lane == 63) wt[t >> 6] = incl;
    __syncthreads();
    if (t == 0) { int run = 0; for (int q = 0; q < 4; ++q) { wp[q] = run; run += wt[q]; } }
    __syncthreads();
    int excl = incl - v + wp[t >> 6] + bboff[b];
    if (i < NN) { off[i] = excl; cur[i] = excl; }
    if (i == 0) off[NN] = NE;
}

__global__ __launch_bounds__(256) void k_perm(const int* __restrict__ dst,
                                              const int* __restrict__ src,
                                              int* __restrict__ cur,
                                              int2* __restrict__ ps) {
    int e = blockIdx.x * 256 + threadIdx.x;
    if (e < NE) {
        int p = atomicAdd(&cur[dst[e]], 1);
        int2 v; v.x = e; v.y = src[e];
        ps[p] = v;
    }
}

// ---------------------------------------------------------------------------
// W pre-split (once per launch): W[k][n] f32 -> Wt_hi[n][k], Wt_lo[n][k] bf16
// ---------------------------------------------------------------------------
__global__ __launch_bounds__(256) void k_wsplit(const float* __restrict__ W,
                                                short* __restrict__ Whi,
                                                short* __restrict__ Wlo) {
    for (int idx = blockIdx.x * 256 + threadIdx.x; idx < D * D; idx += gridDim.x * 256) {
        int n = idx >> 7, k = idx & 127;
        float w = W[k * D + n];
        short hi = f2bf(w);
        Whi[idx] = hi;
        Wlo[idx] = f2bf(w - bf2f(hi));
    }
}

// ---------------------------------------------------------------------------
// Aggregation: one wave per node, 8-edge batched loads.
// h[n] = (1+eps)*x[n] + sum relu(x[src]+ea)   -> d_out (f32)
// ---------------------------------------------------------------------------
__global__ __launch_bounds__(256) void k_agg(const float* __restrict__ x,
                                             const float* __restrict__ ea,
                                             const int* __restrict__ off,
                                             const int2* __restrict__ ps,
                                             const float* __restrict__ eps,
                                             float* __restrict__ h) {
    int wave = threadIdx.x >> 6;
    int lane = threadIdx.x & 63;
    int n = blockIdx.x * 4 + wave;
    if (n >= NN) return;
    int j0 = off[n], j1 = off[n + 1];
    const int lo2 = lane * 2;
    float2 acc; acc.x = 0.0f; acc.y = 0.0f;

    for (int j = j0; j < j1; j += 8) {
        int ee[8], ss[8];
#pragma unroll
        for (int q = 0; q < 8; ++q) {
            int jj = j + q; jj = (jj < j1) ? jj : (j1 - 1);
            int2 p = ps[jj];
            ee[q] = p.x; ss[q] = p.y;
        }
        float2 xa[8], eb[8];
#pragma unroll
        for (int q = 0; q < 8; ++q) {
            xa[q] = *reinterpret_cast<const float2*>(x  + (size_t)ss[q] * D + lo2);
            eb[q] = *reinterpret_cast<const float2*>(ea + (size_t)ee[q] * D + lo2);
        }
#pragma unroll
        for (int q = 0; q < 8; ++q) {
            float mx = fmaxf(xa[q].x + eb[q].x, 0.0f);
            float my = fmaxf(xa[q].y + eb[q].y, 0.0f);
            bool ok = (j + q) < j1;
            acc.x += ok ? mx : 0.0f;
            acc.y += ok ? my : 0.0f;
        }
    }
    float sc = 1.0f + eps[0];
    float2 xx = *reinterpret_cast<const float2*>(x + (size_t)n * D + lo2);
    float2 o;
    o.x = fmaf(sc, xx.x, acc.x);
    o.y = fmaf(sc, xx.y, acc.y);
    *reinterpret_cast<float2*>(h + (size_t)n * D + lo2) = o;
}

// ---------------------------------------------------------------------------
// Fused 2-layer MLP via bf16x3 MFMA.
//   out = (relu(A @ W1 + b1)) @ W2 + b2
// Block: 256 thr = 4 waves; 128 rows/block (wave owns rows [w*32, w*32+32)).
// W fragments read directly from pre-split global planes (L2-resident).
// Layer-1 -> layer-2 handoff via per-wave-private LDS tile (no HBM g buffer):
// wave w's layer-1 D rows are exactly wave w's layer-2 A rows.
// ---------------------------------------------------------------------------
__global__ __launch_bounds__(256) void k_mlp2(const float* __restrict__ A,
                                              const short* __restrict__ W1h,
                                              const short* __restrict__ W1l,
                                              const short* __restrict__ W2h,
                                              const short* __restrict__ W2l,
                                              const float* __restrict__ b1,
                                              const float* __restrict__ b2,
                                              float* __restrict__ out) {
    __shared__ float G[4][32][D];  // 64 KB, per-wave 16 KB tiles

    const int wave = threadIdx.x >> 6;
    const int lane = threadIdx.x & 63;
    const int r = lane & 15;   // A-row / B-col within 16-tile
    const int g = lane >> 4;   // k-group (8 k) / D-row group (4 rows)

    const long rb = (long)blockIdx.x * 128 + wave * 32;  // wave's first row

    // ---------------- layer 1 ----------------
    f32x4 acc1[2][8];
#pragma unroll
    for (int mt = 0; mt < 2; ++mt)
#pragma unroll
        for (int nt = 0; nt < 8; ++nt) {
            acc1[mt][nt].x = 0.f; acc1[mt][nt].y = 0.f;
            acc1[mt][nt].z = 0.f; acc1[mt][nt].w = 0.f;
        }

#pragma unroll
    for (int kc = 0; kc < 4; ++kc) {
        const int k0 = kc * 32;
        bf16x8 ahi[2], alo[2];
#pragma unroll
        for (int mt = 0; mt < 2; ++mt) {
            long row = rb + mt * 16 + r;
            row = (row < NN) ? row : (NN - 1);
            const float* ap = A + row * D + k0 + g * 8;
            float4 v0 = reinterpret_cast<const float4*>(ap)[0];
            float4 v1 = reinterpret_cast<const float4*>(ap)[1];
            float vals[8] = {v0.x, v0.y, v0.z, v0.w, v1.x, v1.y, v1.z, v1.w};
#pragma unroll
            for (int i = 0; i < 8; ++i) {
                short hb = f2bf(vals[i]);
                ahi[mt][i] = hb;
                alo[mt][i] = f2bf(vals[i] - bf2f(hb));
            }
        }
#pragma unroll
        for (int nt = 0; nt < 8; ++nt) {
            const int wb = (nt * 16 + r) * D + k0 + g * 8;
            bf16x8 whi = *reinterpret_cast<const bf16x8*>(&W1h[wb]);
            bf16x8 wlo = *reinterpret_cast<const bf16x8*>(&W1l[wb]);
#pragma unroll
            for (int mt = 0; mt < 2; ++mt) {
                acc1[mt][nt] = __builtin_amdgcn_mfma_f32_16x16x32_bf16(ahi[mt], whi, acc1[mt][nt], 0, 0, 0);
                acc1[mt][nt] = __builtin_amdgcn_mfma_f32_16x16x32_bf16(ahi[mt], wlo, acc1[mt][nt], 0, 0, 0);
                acc1[mt][nt] = __builtin_amdgcn_mfma_f32_16x16x32_bf16(alo[mt], whi, acc1[mt][nt], 0, 0, 0);
            }
        }
    }

    // epilogue 1: bias + relu -> per-wave LDS tile (D row = g*4+q, col = nt*16+r)
#pragma unroll
    for (int nt = 0; nt < 8; ++nt) {
        const int col = nt * 16 + r;
        const float bb = b1[col];
#pragma unroll
        for (int mt = 0; mt < 2; ++mt) {
#pragma unroll
            for (int q = 0; q < 4; ++q) {
                float v = fmaxf(acc1[mt][nt][q] + bb, 0.0f);
                G[wave][mt * 16 + g * 4 + q][col] = v;
            }
        }
    }
    __syncthreads();

    // ---------------- layer 2 ----------------
    f32x4 acc2[2][8];
#pragma unroll
    for (int mt = 0; mt < 2; ++mt)
#pragma unroll
        for (int nt = 0; nt < 8; ++nt) {
            acc2[mt][nt].x = 0.f; acc2[mt][nt].y = 0.f;
            acc2[mt][nt].z = 0.f; acc2[mt][nt].w = 0.f;
        }

#pragma unroll
    for (int kc = 0; kc < 4; ++kc) {
        const int k0 = kc * 32;
        bf16x8 ahi[2], alo[2];
#pragma unroll
        for (int mt = 0; mt < 2; ++mt) {
            const float* gp = &G[wave][mt * 16 + r][k0 + g * 8];
            float4 v0 = reinterpret_cast<const float4*>(gp)[0];
            float4 v1 = reinterpret_cast<const float4*>(gp)[1];
            float vals[8] = {v0.x, v0.y, v0.z, v0.w, v1.x, v1.y, v1.z, v1.w};
#pragma unroll
            for (int i = 0; i < 8; ++i) {
                short hb = f2bf(vals[i]);
                ahi[mt][i] = hb;
                alo[mt][i] = f2bf(vals[i] - bf2f(hb));
            }
        }
#pragma unroll
        for (int nt = 0; nt < 8; ++nt) {
            const int wb = (nt * 16 + r) * D + k0 + g * 8;
            bf16x8 whi = *reinterpret_cast<const bf16x8*>(&W2h[wb]);
            bf16x8 wlo = *reinterpret_cast<const bf16x8*>(&W2l[wb]);
#pragma unroll
            for (int mt = 0; mt < 2; ++mt) {
                acc2[mt][nt] = __builtin_amdgcn_mfma_f32_16x16x32_bf16(ahi[mt], whi, acc2[mt][nt], 0, 0, 0);
                acc2[mt][nt] = __builtin_amdgcn_mfma_f32_16x16x32_bf16(ahi[mt], wlo, acc2[mt][nt], 0, 0, 0);
                acc2[mt][nt] = __builtin_amdgcn_mfma_f32_16x16x32_bf16(alo[mt], whi, acc2[mt][nt], 0, 0, 0);
            }
        }
    }

    // epilogue 2: bias -> global
#pragma unroll
    for (int nt = 0; nt < 8; ++nt) {
        const int col = nt * 16 + r;
        const float bb = b2[col];
#pragma unroll
        for (int mt = 0; mt < 2; ++mt) {
#pragma unroll
            for (int q = 0; q < 4; ++q) {
                long row = rb + mt * 16 + g * 4 + q;
                if (row < NN) out[row * D + col] = acc2[mt][nt][q] + bb;
            }
        }
    }
}

// ---------------------------------------------------------------------------
extern "C" void kernel_launch(void* const* d_in, const int* in_sizes, int n_in,
                              void* d_out, int out_size, void* d_ws, size_t ws_size,
                              hipStream_t stream) {
    const float* x   = (const float*)d_in[0];
    const int*   ei  = (const int*)d_in[1];   // int32 [2, NE]
    const float* ea  = (const float*)d_in[2];
    const float* eps = (const float*)d_in[3];
    const float* W1  = (const float*)d_in[4];
    const float* b1  = (const float*)d_in[5];
    const float* W2  = (const float*)d_in[6];
    const float* b2  = (const float*)d_in[7];
    float* out = (float*)d_out;

    const int* src = ei;
    const int* dst = ei + NE;

    // ws layout
    int* base  = (int*)d_ws;
    int* cnt   = base;                 // NN
    int* off   = cnt + NN;             // NN+1
    int* cur   = off + NN + 1;         // NN
    int* bsum  = cur + NN;             // NB
    int* bboff = bsum + NB;            // NB
    size_t ps_off = ((size_t)(3 * NN + 1 + 2 * NB) + 1) & ~(size_t)1;
    int2* ps   = (int2*)(base + ps_off);          // NE int2
    short* wsp = (short*)(base + ps_off + 2 * (size_t)NE);
    short* W1h = wsp;                  // D*D each
    short* W1l = W1h + D * D;
    short* W2h = W1l + D * D;
    short* W2l = W2h + D * D;

    k_wsplit    <<<32,               256, 0, stream>>>(W1, W1h, W1l);
    k_wsplit    <<<32,               256, 0, stream>>>(W2, W2h, W2l);
    k_zero      <<<NB,               256, 0, stream>>>(cnt);
    k_hist      <<<(NE + 255) / 256, 256, 0, stream>>>(dst, cnt);
    k_bsum      <<<NB,               256, 0, stream>>>(cnt, bsum);
    k_scan_bsum <<<1,                512, 0, stream>>>(bsum, bboff);
    k_scan_final<<<NB,               256, 0, stream>>>(cnt, bboff, off, cur);
    k_perm      <<<(NE + 255) / 256, 256, 0, stream>>>(dst, src, cur, ps);

    // h -> d_out
    k_agg<<<(NN + 3) / 4, 256, 0, stream>>>(x, ea, off, ps, eps, out);
    // out = relu(out @ W1 + b1) @ W2 + b2   (fused, g tile stays in LDS)
    k_mlp2<<<(NN + 127) / 128, 256, 0, stream>>>(out, W1h, W1l, W2h, W2l, b1, b2, out);
}